// Round 9
// baseline (347.111 us; speedup 1.0000x reference)
//
#include <hip/hip_runtime.h>
#include <hip/hip_bf16.h>

// GCN-GRU cell, MI355X. Sizes fixed per reference: B=64, N=2048, H=64.
// Pipeline:
//  1. k_deg      : d[m] = rsqrt(rowsum(adj)+1)
//  2. k_buildA   : A_bf[m][n] = bf16(d[m]*(adj[n][m]+(m==n))*d[n])   (LDS transpose)
//  3. k_buildX1  : X1t[j=b*65+c][n] = bf16(conc[b,n,c]), padded to 4224 rows
//  4. k_zeropad  : zero pad rows 4160..4223
//  5. k_gemm_bt  : ax1[z][m][j] = sum_{n in split z} A_bf[m][n]*X1t[j][n]
//                  SPLIT-K=2 (blockIdx.z): grid 1056 blocks -> ~4 blocks/CU resident
//                  (round-6 profile: 528 blocks, Occupancy 16%, MfmaUtil 18% ->
//                   resident-block-starved at this shape).
//  6. k_out1     : axS = ax1[0]+ax1[1]; sig = sigmoid(axS@W1+b1);
//                  m<1024 -> rh=sig*h (bf16), m>=1024 -> ubuf=sig
//  7. k_y2       : y2 = inp*W2[0,:] + rh@W2[1:,:] -> Y2t (K-major bf16)
//  8. k_gemm_bt  : cpre[z][m][b*64+o] = sum_{n in split z} A_bf[m][n]*Y2t[b*64+o][n]
//  9. k_final    : out = u*h + (1-u)*tanh(cpre[0]+cpre[1] + b2)

typedef __attribute__((ext_vector_type(8))) short short8;
typedef __attribute__((ext_vector_type(4))) float f32x4;

#define NB 64
#define NN 2048
#define NH 64
#define NC1P 4224   // padded 64*65=4160 -> 33*128
#define NC2 4096

__device__ __forceinline__ void gload16(const void* g, void* l) {
  __builtin_amdgcn_global_load_lds((const __attribute__((address_space(1))) void*)g,
                                   (__attribute__((address_space(3))) void*)l, 16, 0, 0);
}

__device__ __forceinline__ unsigned pack_bf16(float a, float b) {
  unsigned ua = __float_as_uint(a), ub = __float_as_uint(b);
  // round-to-nearest-even bf16, matching __float2bfloat16 for normal values
  ua += 0x7fffu + ((ua >> 16) & 1u);
  ub += 0x7fffu + ((ub >> 16) & 1u);
  return (ua >> 16) | (ub & 0xffff0000u);
}

__global__ __launch_bounds__(256) void k_deg(const float* __restrict__ adj,
                                             float* __restrict__ d) {
  __shared__ float red[256];
  int m = blockIdx.x;
  float s = 0.f;
  for (int j = threadIdx.x; j < NN; j += 256) s += adj[(size_t)m * NN + j];
  red[threadIdx.x] = s;
  __syncthreads();
  for (int off = 128; off > 0; off >>= 1) {
    if (threadIdx.x < off) red[threadIdx.x] += red[threadIdx.x + off];
    __syncthreads();
  }
  if (threadIdx.x == 0) {
    float v = rsqrtf(red[0] + 1.0f);
    d[m] = isinf(v) ? 0.f : v;
  }
}

__global__ __launch_bounds__(256) void k_buildA(const float* __restrict__ adj,
                                                const float* __restrict__ d,
                                                __hip_bfloat16* __restrict__ Abf) {
  __shared__ float t[64][65];
  int m0 = blockIdx.x * 64, n0 = blockIdx.y * 64;
  for (int i = threadIdx.x; i < 64 * 64; i += 256) {
    int r = i >> 6, c = i & 63;                   // adj row n0+r, col m0+c
    t[r][c] = adj[(size_t)(n0 + r) * NN + m0 + c];
  }
  __syncthreads();
  for (int i = threadIdx.x; i < 64 * 64; i += 256) {
    int r = i >> 6, c = i & 63;                   // A row m0+r, col n0+c
    int m = m0 + r, n = n0 + c;
    float v = t[c][r] + (m == n ? 1.0f : 0.0f);
    Abf[(size_t)m * NN + n] = __float2bfloat16(d[m] * v * d[n]);
  }
}

__global__ __launch_bounds__(256) void k_buildX1(const float* __restrict__ inp,
                                                 const float* __restrict__ hid,
                                                 __hip_bfloat16* __restrict__ X1t) {
  __shared__ float t[64][65];
  int b = blockIdx.x, n0 = blockIdx.y * 64;
  for (int i = threadIdx.x; i < 64 * 64; i += 256) {
    int r = i >> 6, h = i & 63;
    t[r][h] = hid[((size_t)b * NN + n0 + r) * NH + h];
  }
  __syncthreads();
  for (int i = threadIdx.x; i < 64 * 64; i += 256) {
    int h = i >> 6, r = i & 63;
    X1t[(size_t)(b * 65 + 1 + h) * NN + n0 + r] = __float2bfloat16(t[r][h]);
  }
  if (threadIdx.x < 64) {
    int r = threadIdx.x;
    X1t[(size_t)(b * 65) * NN + n0 + r] = __float2bfloat16(inp[(size_t)b * NN + n0 + r]);
  }
}

__global__ __launch_bounds__(256) void k_zeropad(__hip_bfloat16* __restrict__ X1t) {
  size_t i = (size_t)blockIdx.x * 256 + threadIdx.x;   // 64*2048 elems
  X1t[(size_t)4160 * NN + i] = __float2bfloat16(0.f);
}

// C[z][M x Nc] = A[M x Kslice(z)] * Bt[Nc x Kslice(z)]^T ; bf16 in, f32 out.
// 128x128 tile, BK=32, split-K over blockIdx.z (each split -> own output buffer).
__global__ __launch_bounds__(256) void k_gemm_bt(const __hip_bfloat16* __restrict__ Ag,
                                                 const __hip_bfloat16* __restrict__ Bg,
                                                 float* __restrict__ Cg,
                                                 int Ncdim, int Ksplit) {
  __shared__ char lds[16384];
  char* lA = lds;
  char* lB = lds + 8192;
  const int m0 = blockIdx.x * 128, n0 = blockIdx.y * 128;
  const int koff = blockIdx.z * Ksplit;
  Cg += (size_t)blockIdx.z * NN * Ncdim;
  const int tid = threadIdx.x;
  const int wave = tid >> 6, lane = tid & 63;
  const int wr = wave >> 1, wc = wave & 1;
  const size_t strB = (size_t)NN * 2;  // bytes per row (K = NN always)
  const char* ga0 = (const char*)Ag + (size_t)(m0 + wave * 16 + (lane >> 2)) * strB + (lane & 3) * 16;
  const char* gb0 = (const char*)Bg + (size_t)(n0 + wave * 16 + (lane >> 2)) * strB + (lane & 3) * 16;
  const char* ga1 = ga0 + 64 * strB;
  const char* gb1 = gb0 + 64 * strB;
  char* la0 = lA + wave * 1024;   // wave-uniform LDS base; HW adds lane*16
  char* lb0 = lB + wave * 1024;
  f32x4 acc[4][4] = {};
  const int rowi = lane & 15;
  const int kb = (lane >> 4) * 16;   // byte offset of k-slice within 64B row
  for (int kk = koff; kk < koff + Ksplit; kk += 32) {
    const size_t kb2 = (size_t)kk * 2;
    gload16(ga0 + kb2, la0);
    gload16(ga1 + kb2, la0 + 4096);
    gload16(gb0 + kb2, lb0);
    gload16(gb1 + kb2, lb0 + 4096);
    __syncthreads();
    short8 af[4], bfr[4];
#pragma unroll
    for (int f = 0; f < 4; ++f) {
      af[f]  = *(const short8*)(lA + (wr * 64 + f * 16 + rowi) * 64 + kb);
      bfr[f] = *(const short8*)(lB + (wc * 64 + f * 16 + rowi) * 64 + kb);
    }
#pragma unroll
    for (int i = 0; i < 4; ++i)
#pragma unroll
      for (int j = 0; j < 4; ++j)
        acc[i][j] = __builtin_amdgcn_mfma_f32_16x16x32_bf16(af[i], bfr[j], acc[i][j], 0, 0, 0);
    __syncthreads();
  }
  const int cn = n0 + wc * 64 + (lane & 15);
  const int rb = m0 + wr * 64 + ((lane >> 4) << 2);
#pragma unroll
  for (int i = 0; i < 4; ++i)
#pragma unroll
    for (int j = 0; j < 4; ++j)
#pragma unroll
      for (int r = 0; r < 4; ++r)
        Cg[(size_t)(rb + i * 16 + r) * Ncdim + (cn + j * 16)] = acc[i][j][r];
}

// k_out1 v4: as v3 but sums the two split-K partials of ax1 while staging axS.
// 128 rows/block, 4 rows/thread x 16 h-contiguous outputs.
// sig = sigmoid((ax1[0]+ax1[1])[m][b*65+c] @ W1 + b1)
// mt<8 (m<1024): rh[b][2m+s][h] = sig*hid (bf16)  ; mt>=8: ubuf = sig
__global__ __launch_bounds__(256) void k_out1(const float* __restrict__ ax1,
                                              const float* __restrict__ W1,
                                              const float* __restrict__ b1,
                                              const float* __restrict__ hid,
                                              __hip_bfloat16* __restrict__ rhG,
                                              float* __restrict__ ubuf) {
  __shared__ __align__(16) float W1s[65 * 132];   // 34.3 KB (padded stride)
  __shared__ __align__(16) float axS[128 * 66];   // 33.8 KB
  __shared__ float b1S[128];
  const int b = blockIdx.x, mt = blockIdx.y;      // mt 0..15; <8 -> rh, >=8 -> u
  const bool isRH = (mt < 8);
  const int mh0 = (mt & 7) * 128;                 // row offset within half
  const int mabs0 = (isRH ? 0 : 1024) + mh0;      // ax1 absolute row
  const int t = threadIdx.x;
  const float* __restrict__ ax1b = ax1 + (size_t)NN * NC1P;   // split-K partial 1
  for (int i = t; i < 65 * 128; i += 256) {
    int r = i >> 7, x = i & 127;
    W1s[r * 132 + x] = W1[i];
  }
  if (t < 128) b1S[t] = b1[t];
  for (int i = t; i < 128 * 65; i += 256) {
    int r = i / 65, c = i - r * 65;
    const size_t gi = (size_t)(mabs0 + r) * NC1P + b * 65 + c;
    axS[r * 66 + c] = ax1[gi] + ax1b[gi];
  }
  __syncthreads();
  const int rq = t >> 3, og = t & 7;              // rq 0..31, og 0..7
  const int ob = og * 16;
  float acc[4][16];
#pragma unroll
  for (int q = 0; q < 4; ++q)
#pragma unroll
    for (int k = 0; k < 16; ++k) acc[q][k] = 0.f;
  int co = og;                                    // staggered start; wraps at 65
  for (int c = 0; c < 65; ++c) {
    const float a0 = axS[rq * 66 + co];
    const float a1 = axS[(rq + 32) * 66 + co];
    const float a2 = axS[(rq + 64) * 66 + co];
    const float a3 = axS[(rq + 96) * 66 + co];
    const float* wrow = &W1s[co * 132 + ob];
#pragma unroll
    for (int kq = 0; kq < 4; ++kq) {
      const float4 w = *(const float4*)&wrow[kq * 4];
      acc[0][kq * 4 + 0] += a0 * w.x;  acc[0][kq * 4 + 1] += a0 * w.y;
      acc[0][kq * 4 + 2] += a0 * w.z;  acc[0][kq * 4 + 3] += a0 * w.w;
      acc[1][kq * 4 + 0] += a1 * w.x;  acc[1][kq * 4 + 1] += a1 * w.y;
      acc[1][kq * 4 + 2] += a1 * w.z;  acc[1][kq * 4 + 3] += a1 * w.w;
      acc[2][kq * 4 + 0] += a2 * w.x;  acc[2][kq * 4 + 1] += a2 * w.y;
      acc[2][kq * 4 + 2] += a2 * w.z;  acc[2][kq * 4 + 3] += a2 * w.w;
      acc[3][kq * 4 + 0] += a3 * w.x;  acc[3][kq * 4 + 1] += a3 * w.y;
      acc[3][kq * 4 + 2] += a3 * w.z;  acc[3][kq * 4 + 3] += a3 * w.w;
    }
    co = (co == 64) ? 0 : co + 1;
  }
  const int s = og >> 2;                          // node parity
  const int h0 = (og & 3) * 16;                   // h base (contiguous 16)
#pragma unroll
  for (int q = 0; q < 4; ++q) {
    const int rl = rq + 32 * q;                   // row_local 0..127
    float s16[16];
#pragma unroll
    for (int k = 0; k < 16; ++k) {
      const float v = acc[q][k] + b1S[ob + k];
      s16[k] = 1.0f / (1.0f + __expf(-v));
    }
    const int n = 2 * (mh0 + rl) + s;
    const size_t idx = ((size_t)b * NN + n) * NH + h0;
    if (isRH) {
      const float4 h0v = *(const float4*)&hid[idx];
      const float4 h1v = *(const float4*)&hid[idx + 4];
      const float4 h2v = *(const float4*)&hid[idx + 8];
      const float4 h3v = *(const float4*)&hid[idx + 12];
      uint4 p0, p1;
      p0.x = pack_bf16(s16[0] * h0v.x,  s16[1] * h0v.y);
      p0.y = pack_bf16(s16[2] * h0v.z,  s16[3] * h0v.w);
      p0.z = pack_bf16(s16[4] * h1v.x,  s16[5] * h1v.y);
      p0.w = pack_bf16(s16[6] * h1v.z,  s16[7] * h1v.w);
      p1.x = pack_bf16(s16[8] * h2v.x,  s16[9] * h2v.y);
      p1.y = pack_bf16(s16[10] * h2v.z, s16[11] * h2v.w);
      p1.z = pack_bf16(s16[12] * h3v.x, s16[13] * h3v.y);
      p1.w = pack_bf16(s16[14] * h3v.z, s16[15] * h3v.w);
      *(uint4*)&rhG[idx] = p0;
      *(uint4*)&rhG[idx + 8] = p1;
    } else {
      *(float4*)&ubuf[idx]      = make_float4(s16[0], s16[1], s16[2], s16[3]);
      *(float4*)&ubuf[idx + 4]  = make_float4(s16[4], s16[5], s16[6], s16[7]);
      *(float4*)&ubuf[idx + 8]  = make_float4(s16[8], s16[9], s16[10], s16[11]);
      *(float4*)&ubuf[idx + 12] = make_float4(s16[12], s16[13], s16[14], s16[15]);
    }
  }
}

// k_y2 v2: y2[b][n][o2] = inp[b][n]*W2[0][o2] + sum_h rh[b][n][h]*W2[1+h][o2]
// -> Y2t[b*64+o2][n] bf16, staged in LDS as packed pairs, coalesced uint writes.
// Thread: np=t>>2 owns ADJACENT nodes {2np, 2np+1}; og2=t&3 owns 16 outputs.
__global__ __launch_bounds__(256) void k_y2(const __hip_bfloat16* __restrict__ rhG,
                                            const float* __restrict__ inp,
                                            const float* __restrict__ W2,
                                            __hip_bfloat16* __restrict__ Y2t) {
  __shared__ __align__(16) float W2s[65 * 64];        // 16.6 KB
  __shared__ __align__(16) float rhS[128 * 66];       // 33.8 KB
  __shared__ __align__(16) unsigned y2S[64 * 65];     // 16.6 KB [o2][node_pair]
  __shared__ float inpS[128];
  const int b = blockIdx.x, nt = blockIdx.y;
  const int n0 = nt * 128;
  const int t = threadIdx.x;
  for (int i = t; i < 65 * 64; i += 256) W2s[i] = W2[i];
  for (int i = t; i < 128 * 32; i += 256) {
    const int nl = i >> 5, hp = (i & 31) * 2;
    const unsigned v = *(const unsigned*)&rhG[((size_t)b * NN + n0 + nl) * NH + hp];
    rhS[nl * 66 + hp]     = __uint_as_float((v & 0xffffu) << 16);
    rhS[nl * 66 + hp + 1] = __uint_as_float(v & 0xffff0000u);
  }
  if (t < 128) inpS[t] = inp[(size_t)b * NN + n0 + t];
  __syncthreads();
  const int np = t >> 2, og2 = t & 3;   // np in 0..63 -> nodes 2np, 2np+1
  float acc[2][16];
  {
    const float i0 = inpS[2 * np], i1 = inpS[2 * np + 1];
#pragma unroll
    for (int kq = 0; kq < 4; ++kq) {
      const int kq2 = (kq + og2) & 3;
      const float4 w = *(const float4*)&W2s[og2 * 16 + kq2 * 4];  // W2 row 0 = input weight
      acc[0][kq * 4 + 0] = i0 * w.x;  acc[1][kq * 4 + 0] = i1 * w.x;
      acc[0][kq * 4 + 1] = i0 * w.y;  acc[1][kq * 4 + 1] = i1 * w.y;
      acc[0][kq * 4 + 2] = i0 * w.z;  acc[1][kq * 4 + 2] = i1 * w.z;
      acc[0][kq * 4 + 3] = i0 * w.w;  acc[1][kq * 4 + 3] = i1 * w.w;
    }
  }
  for (int c = 0; c < 64; ++c) {
    const float r0 = rhS[(2 * np) * 66 + c];
    const float r1 = rhS[(2 * np + 1) * 66 + c];
#pragma unroll
    for (int kq = 0; kq < 4; ++kq) {
      const int kq2 = (kq + og2) & 3;
      const float4 w = *(const float4*)&W2s[(c + 1) * 64 + og2 * 16 + kq2 * 4];
      acc[0][kq * 4 + 0] += r0 * w.x;  acc[1][kq * 4 + 0] += r1 * w.x;
      acc[0][kq * 4 + 1] += r0 * w.y;  acc[1][kq * 4 + 1] += r1 * w.y;
      acc[0][kq * 4 + 2] += r0 * w.z;  acc[1][kq * 4 + 2] += r1 * w.z;
      acc[0][kq * 4 + 3] += r0 * w.w;  acc[1][kq * 4 + 3] += r1 * w.w;
    }
  }
  // Stage packed bf16 pairs: y2S[o2][np] = (node 2np, node 2np+1)
#pragma unroll
  for (int kq = 0; kq < 4; ++kq) {
    const int kq2 = (kq + og2) & 3;
#pragma unroll
    for (int j = 0; j < 4; ++j) {
      const int o2 = og2 * 16 + kq2 * 4 + j;
      y2S[o2 * 65 + np] = pack_bf16(acc[0][kq * 4 + j], acc[1][kq * 4 + j]);
    }
  }
  __syncthreads();
  // Coalesced writeback: 64 rows x 64 uints (128 nodes) each.
  for (int i = t; i < 64 * 64; i += 256) {
    const int o2 = i >> 6, npair = i & 63;
    *(unsigned*)&Y2t[(size_t)(b * 64 + o2) * NN + n0 + 2 * npair] = y2S[o2 * 65 + npair];
  }
}

__global__ __launch_bounds__(256) void k_final(const float* __restrict__ cpre,
                                               const float* __restrict__ ubuf,
                                               const float* __restrict__ hid,
                                               const float* __restrict__ b2,
                                               float* __restrict__ out) {
  size_t i4 = (size_t)blockIdx.x * 256 + threadIdx.x;  // 2,097,152 threads
  size_t base = i4 * 4;
  int b = (int)(base / (NN * NH));
  int rem = (int)(base % (NN * NH));
  int n = rem / NH, h0 = rem % NH;
  const float4 u = *(const float4*)&ubuf[base];
  const float4 hv = *(const float4*)&hid[base];
  const size_t ci = (size_t)n * NC2 + b * 64 + h0;
  const float4 cp0 = *(const float4*)&cpre[ci];
  const float4 cp1 = *(const float4*)&cpre[(size_t)NN * NC2 + ci];
  const float4 bb = *(const float4*)&b2[h0];
  float4 r;
  r.x = u.x * hv.x + (1.f - u.x) * tanhf(cp0.x + cp1.x + bb.x);
  r.y = u.y * hv.y + (1.f - u.y) * tanhf(cp0.y + cp1.y + bb.y);
  r.z = u.z * hv.z + (1.f - u.z) * tanhf(cp0.z + cp1.z + bb.z);
  r.w = u.w * hv.w + (1.f - u.w) * tanhf(cp0.w + cp1.w + bb.w);
  *(float4*)&out[base] = r;
}

extern "C" void kernel_launch(void* const* d_in, const int* in_sizes, int n_in,
                              void* d_out, int out_size, void* d_ws, size_t ws_size,
                              hipStream_t stream) {
  const float* inp = (const float*)d_in[0];
  const float* hid = (const float*)d_in[1];
  const float* adj = (const float*)d_in[2];
  const float* W1  = (const float*)d_in[3];
  const float* b1  = (const float*)d_in[4];
  const float* W2  = (const float*)d_in[5];
  const float* b2  = (const float*)d_in[6];
  float* out = (float*)d_out;

  char* w = (char*)d_ws;
  float* dd            = (float*)w;                       w += 8192;
  __hip_bfloat16* Abf  = (__hip_bfloat16*)w;              w += (size_t)NN * NN * 2;            // 8.39 MB
  __hip_bfloat16* X1t  = (__hip_bfloat16*)w;              w += (size_t)NC1P * NN * 2;          // 17.3 MB
  float* ax1           = (float*)w;                       w += (size_t)2 * NN * NC1P * 4;      // 69.2 MB (2 split-K partials)
  __hip_bfloat16* Y2t  = (__hip_bfloat16*)w;              w += (size_t)NC2 * NN * 2;           // 16.8 MB
  float* ubuf          = (float*)w;                       w += (size_t)NB * NN * NH * 4;       // 33.6 MB
  float* cpre          = ax1;                 // ax1 dead after k_out1; 2x33.5MB fits in 69.2
  __hip_bfloat16* rhG  = X1t;                 // X1t dead after GEMM1 (16.78 MB <= 17.3 MB)

  k_deg<<<NN, 256, 0, stream>>>(adj, dd);
  k_buildA<<<dim3(32, 32), 256, 0, stream>>>(adj, dd, Abf);
  k_buildX1<<<dim3(NB, 32), 256, 0, stream>>>(inp, hid, X1t);
  k_zeropad<<<512, 256, 0, stream>>>(X1t);
  k_gemm_bt<<<dim3(16, 33, 2), 256, 0, stream>>>(Abf, X1t, ax1, NC1P, NN / 2);
  k_out1<<<dim3(NB, 16), 256, 0, stream>>>(ax1, W1, b1, hid, rhG, ubuf);
  k_y2<<<dim3(NB, 16), 256, 0, stream>>>(rhG, inp, W2, Y2t);
  k_gemm_bt<<<dim3(16, 32, 2), 256, 0, stream>>>(Abf, Y2t, cpre, NC2, NN / 2);
  k_final<<<8192, 256, 0, stream>>>(cpre, ubuf, hid, b2, out);
}

// Round 10
// 329.076 us; speedup vs baseline: 1.0548x; 1.0548x over previous
//
#include <hip/hip_runtime.h>
#include <hip/hip_bf16.h>

// GCN-GRU cell, MI355X. Sizes fixed per reference: B=64, N=2048, H=64.
// Pipeline:
//  1. k_deg      : d[m] = rsqrt(rowsum(adj)+1)
//  2. k_buildA   : A_bf[m][n] = bf16(d[m]*(adj[n][m]+(m==n))*d[n])   (LDS transpose)
//  3. k_buildX1  : X1t[j=b*65+c][n] = bf16(conc[b,n,c]), padded to 4224 rows
//  4. k_zeropad  : zero pad rows 4160..4223
//  5. k_gemm_bt  : ax1[z][m][j] = sum_{n in split z} A_bf[m][n]*X1t[j][n]
//                  SPLIT-K=2 + v2: 2-PHASE DOUBLE-BUFFERED K-loop — issue next
//                  tile's global_load_lds BEFORE computing current tile; ONE
//                  __syncthreads per K-step (round-9 profile: MfmaUtil 19.7%,
//                  Occupancy 26% -> exposed vmcnt(0) drain at barrier-1 was the
//                  critical path, not residency).
//  6. k_out1     : axS = ax1[0]+ax1[1]; sig = sigmoid(axS@W1+b1);
//                  m<1024 -> rh=sig*h (bf16), m>=1024 -> ubuf=sig
//  7. k_y2       : y2 = inp*W2[0,:] + rh@W2[1:,:] -> Y2t (K-major bf16)
//  8. k_gemm_bt  : cpre[z][m][b*64+o] = sum_{n in split z} A_bf[m][n]*Y2t[b*64+o][n]
//  9. k_final    : out = u*h + (1-u)*tanh(cpre[0]+cpre[1] + b2)

typedef __attribute__((ext_vector_type(8))) short short8;
typedef __attribute__((ext_vector_type(4))) float f32x4;

#define NB 64
#define NN 2048
#define NH 64
#define NC1P 4224   // padded 64*65=4160 -> 33*128
#define NC2 4096

__device__ __forceinline__ void gload16(const void* g, void* l) {
  __builtin_amdgcn_global_load_lds((const __attribute__((address_space(1))) void*)g,
                                   (__attribute__((address_space(3))) void*)l, 16, 0, 0);
}

__device__ __forceinline__ unsigned pack_bf16(float a, float b) {
  unsigned ua = __float_as_uint(a), ub = __float_as_uint(b);
  // round-to-nearest-even bf16, matching __float2bfloat16 for normal values
  ua += 0x7fffu + ((ua >> 16) & 1u);
  ub += 0x7fffu + ((ub >> 16) & 1u);
  return (ua >> 16) | (ub & 0xffff0000u);
}

__global__ __launch_bounds__(256) void k_deg(const float* __restrict__ adj,
                                             float* __restrict__ d) {
  __shared__ float red[256];
  int m = blockIdx.x;
  float s = 0.f;
  for (int j = threadIdx.x; j < NN; j += 256) s += adj[(size_t)m * NN + j];
  red[threadIdx.x] = s;
  __syncthreads();
  for (int off = 128; off > 0; off >>= 1) {
    if (threadIdx.x < off) red[threadIdx.x] += red[threadIdx.x + off];
    __syncthreads();
  }
  if (threadIdx.x == 0) {
    float v = rsqrtf(red[0] + 1.0f);
    d[m] = isinf(v) ? 0.f : v;
  }
}

__global__ __launch_bounds__(256) void k_buildA(const float* __restrict__ adj,
                                                const float* __restrict__ d,
                                                __hip_bfloat16* __restrict__ Abf) {
  __shared__ float t[64][65];
  int m0 = blockIdx.x * 64, n0 = blockIdx.y * 64;
  for (int i = threadIdx.x; i < 64 * 64; i += 256) {
    int r = i >> 6, c = i & 63;                   // adj row n0+r, col m0+c
    t[r][c] = adj[(size_t)(n0 + r) * NN + m0 + c];
  }
  __syncthreads();
  for (int i = threadIdx.x; i < 64 * 64; i += 256) {
    int r = i >> 6, c = i & 63;                   // A row m0+r, col n0+c
    int m = m0 + r, n = n0 + c;
    float v = t[c][r] + (m == n ? 1.0f : 0.0f);
    Abf[(size_t)m * NN + n] = __float2bfloat16(d[m] * v * d[n]);
  }
}

__global__ __launch_bounds__(256) void k_buildX1(const float* __restrict__ inp,
                                                 const float* __restrict__ hid,
                                                 __hip_bfloat16* __restrict__ X1t) {
  __shared__ float t[64][65];
  int b = blockIdx.x, n0 = blockIdx.y * 64;
  for (int i = threadIdx.x; i < 64 * 64; i += 256) {
    int r = i >> 6, h = i & 63;
    t[r][h] = hid[((size_t)b * NN + n0 + r) * NH + h];
  }
  __syncthreads();
  for (int i = threadIdx.x; i < 64 * 64; i += 256) {
    int h = i >> 6, r = i & 63;
    X1t[(size_t)(b * 65 + 1 + h) * NN + n0 + r] = __float2bfloat16(t[r][h]);
  }
  if (threadIdx.x < 64) {
    int r = threadIdx.x;
    X1t[(size_t)(b * 65) * NN + n0 + r] = __float2bfloat16(inp[(size_t)b * NN + n0 + r]);
  }
}

__global__ __launch_bounds__(256) void k_zeropad(__hip_bfloat16* __restrict__ X1t) {
  size_t i = (size_t)blockIdx.x * 256 + threadIdx.x;   // 64*2048 elems
  X1t[(size_t)4160 * NN + i] = __float2bfloat16(0.f);
}

// C[z][M x Nc] = A[M x Kslice(z)] * Bt[Nc x Kslice(z)]^T ; bf16 in, f32 out.
// 128x128 tile, BK=32, split-K over blockIdx.z.
// v2: double-buffered LDS (2 x 16KB), 2-phase schedule:
//   prologue: STAGE(buf0, t0); barrier
//   loop:     STAGE(buf^1, t+1); ds_read buf; MFMA; barrier; flip
//   epilogue: compute last tile (no barrier)
// The single barrier's vmcnt(0) drain lands AFTER ds_read+MFMA have covered
// the load latency (issue-early / wait-late).
__global__ __launch_bounds__(256) void k_gemm_bt(const __hip_bfloat16* __restrict__ Ag,
                                                 const __hip_bfloat16* __restrict__ Bg,
                                                 float* __restrict__ Cg,
                                                 int Ncdim, int Ksplit) {
  __shared__ char lds[32768];   // [2 buffers][A 8KB | B 8KB]
  const int m0 = blockIdx.x * 128, n0 = blockIdx.y * 128;
  const int koff = blockIdx.z * Ksplit;
  Cg += (size_t)blockIdx.z * NN * Ncdim;
  const int tid = threadIdx.x;
  const int wave = tid >> 6, lane = tid & 63;
  const int wr = wave >> 1, wc = wave & 1;
  const size_t strB = (size_t)NN * 2;  // bytes per row (K = NN always)
  const char* ga0 = (const char*)Ag + (size_t)(m0 + wave * 16 + (lane >> 2)) * strB + (lane & 3) * 16;
  const char* gb0 = (const char*)Bg + (size_t)(n0 + wave * 16 + (lane >> 2)) * strB + (lane & 3) * 16;
  const char* ga1 = ga0 + 64 * strB;
  const char* gb1 = gb0 + 64 * strB;
  char* const lw = lds + wave * 1024;   // wave-uniform LDS base; HW adds lane*16
  f32x4 acc[4][4] = {};
  const int rowi = lane & 15;
  const int kb = (lane >> 4) * 16;      // byte offset of k-slice within 64B row

  // prologue: stage tile 0 into buffer 0
  {
    const size_t kb2 = (size_t)koff * 2;
    gload16(ga0 + kb2, lw);
    gload16(ga1 + kb2, lw + 4096);
    gload16(gb0 + kb2, lw + 8192);
    gload16(gb1 + kb2, lw + 12288);
  }
  __syncthreads();
  int cur = 0;
  for (int kk = koff + 32; kk < koff + Ksplit; kk += 32) {
    // phase 1: issue next-tile loads into the other buffer (overlap with compute)
    {
      char* ldst = lw + (cur ^ 1) * 16384;
      const size_t kb2 = (size_t)kk * 2;
      gload16(ga0 + kb2, ldst);
      gload16(ga1 + kb2, ldst + 4096);
      gload16(gb0 + kb2, ldst + 8192);
      gload16(gb1 + kb2, ldst + 12288);
    }
    // phase 2: compute current buffer
    const char* lA = lds + cur * 16384;
    const char* lB = lA + 8192;
    short8 af[4], bfr[4];
#pragma unroll
    for (int f = 0; f < 4; ++f) {
      af[f]  = *(const short8*)(lA + (wr * 64 + f * 16 + rowi) * 64 + kb);
      bfr[f] = *(const short8*)(lB + (wc * 64 + f * 16 + rowi) * 64 + kb);
    }
#pragma unroll
    for (int i = 0; i < 4; ++i)
#pragma unroll
      for (int j = 0; j < 4; ++j)
        acc[i][j] = __builtin_amdgcn_mfma_f32_16x16x32_bf16(af[i], bfr[j], acc[i][j], 0, 0, 0);
    __syncthreads();   // drains next-tile loads (vmcnt) + this-tile reads (lgkm)
    cur ^= 1;
  }
  // epilogue: last tile already staged
  {
    const char* lA = lds + cur * 16384;
    const char* lB = lA + 8192;
    short8 af[4], bfr[4];
#pragma unroll
    for (int f = 0; f < 4; ++f) {
      af[f]  = *(const short8*)(lA + (wr * 64 + f * 16 + rowi) * 64 + kb);
      bfr[f] = *(const short8*)(lB + (wc * 64 + f * 16 + rowi) * 64 + kb);
    }
#pragma unroll
    for (int i = 0; i < 4; ++i)
#pragma unroll
      for (int j = 0; j < 4; ++j)
        acc[i][j] = __builtin_amdgcn_mfma_f32_16x16x32_bf16(af[i], bfr[j], acc[i][j], 0, 0, 0);
  }
  const int cn = n0 + wc * 64 + (lane & 15);
  const int rb = m0 + wr * 64 + ((lane >> 4) << 2);
#pragma unroll
  for (int i = 0; i < 4; ++i)
#pragma unroll
    for (int j = 0; j < 4; ++j)
#pragma unroll
      for (int r = 0; r < 4; ++r)
        Cg[(size_t)(rb + i * 16 + r) * Ncdim + (cn + j * 16)] = acc[i][j][r];
}

// k_out1 v4: sums the two split-K partials of ax1 while staging axS.
// 128 rows/block, 4 rows/thread x 16 h-contiguous outputs.
// sig = sigmoid((ax1[0]+ax1[1])[m][b*65+c] @ W1 + b1)
// mt<8 (m<1024): rh[b][2m+s][h] = sig*hid (bf16)  ; mt>=8: ubuf = sig
__global__ __launch_bounds__(256) void k_out1(const float* __restrict__ ax1,
                                              const float* __restrict__ W1,
                                              const float* __restrict__ b1,
                                              const float* __restrict__ hid,
                                              __hip_bfloat16* __restrict__ rhG,
                                              float* __restrict__ ubuf) {
  __shared__ __align__(16) float W1s[65 * 132];   // 34.3 KB (padded stride)
  __shared__ __align__(16) float axS[128 * 66];   // 33.8 KB
  __shared__ float b1S[128];
  const int b = blockIdx.x, mt = blockIdx.y;      // mt 0..15; <8 -> rh, >=8 -> u
  const bool isRH = (mt < 8);
  const int mh0 = (mt & 7) * 128;                 // row offset within half
  const int mabs0 = (isRH ? 0 : 1024) + mh0;      // ax1 absolute row
  const int t = threadIdx.x;
  const float* __restrict__ ax1b = ax1 + (size_t)NN * NC1P;   // split-K partial 1
  for (int i = t; i < 65 * 128; i += 256) {
    int r = i >> 7, x = i & 127;
    W1s[r * 132 + x] = W1[i];
  }
  if (t < 128) b1S[t] = b1[t];
  for (int i = t; i < 128 * 65; i += 256) {
    int r = i / 65, c = i - r * 65;
    const size_t gi = (size_t)(mabs0 + r) * NC1P + b * 65 + c;
    axS[r * 66 + c] = ax1[gi] + ax1b[gi];
  }
  __syncthreads();
  const int rq = t >> 3, og = t & 7;              // rq 0..31, og 0..7
  const int ob = og * 16;
  float acc[4][16];
#pragma unroll
  for (int q = 0; q < 4; ++q)
#pragma unroll
    for (int k = 0; k < 16; ++k) acc[q][k] = 0.f;
  int co = og;                                    // staggered start; wraps at 65
  for (int c = 0; c < 65; ++c) {
    const float a0 = axS[rq * 66 + co];
    const float a1 = axS[(rq + 32) * 66 + co];
    const float a2 = axS[(rq + 64) * 66 + co];
    const float a3 = axS[(rq + 96) * 66 + co];
    const float* wrow = &W1s[co * 132 + ob];
#pragma unroll
    for (int kq = 0; kq < 4; ++kq) {
      const float4 w = *(const float4*)&wrow[kq * 4];
      acc[0][kq * 4 + 0] += a0 * w.x;  acc[0][kq * 4 + 1] += a0 * w.y;
      acc[0][kq * 4 + 2] += a0 * w.z;  acc[0][kq * 4 + 3] += a0 * w.w;
      acc[1][kq * 4 + 0] += a1 * w.x;  acc[1][kq * 4 + 1] += a1 * w.y;
      acc[1][kq * 4 + 2] += a1 * w.z;  acc[1][kq * 4 + 3] += a1 * w.w;
      acc[2][kq * 4 + 0] += a2 * w.x;  acc[2][kq * 4 + 1] += a2 * w.y;
      acc[2][kq * 4 + 2] += a2 * w.z;  acc[2][kq * 4 + 3] += a2 * w.w;
      acc[3][kq * 4 + 0] += a3 * w.x;  acc[3][kq * 4 + 1] += a3 * w.y;
      acc[3][kq * 4 + 2] += a3 * w.z;  acc[3][kq * 4 + 3] += a3 * w.w;
    }
    co = (co == 64) ? 0 : co + 1;
  }
  const int s = og >> 2;                          // node parity
  const int h0 = (og & 3) * 16;                   // h base (contiguous 16)
#pragma unroll
  for (int q = 0; q < 4; ++q) {
    const int rl = rq + 32 * q;                   // row_local 0..127
    float s16[16];
#pragma unroll
    for (int k = 0; k < 16; ++k) {
      const float v = acc[q][k] + b1S[ob + k];
      s16[k] = 1.0f / (1.0f + __expf(-v));
    }
    const int n = 2 * (mh0 + rl) + s;
    const size_t idx = ((size_t)b * NN + n) * NH + h0;
    if (isRH) {
      const float4 h0v = *(const float4*)&hid[idx];
      const float4 h1v = *(const float4*)&hid[idx + 4];
      const float4 h2v = *(const float4*)&hid[idx + 8];
      const float4 h3v = *(const float4*)&hid[idx + 12];
      uint4 p0, p1;
      p0.x = pack_bf16(s16[0] * h0v.x,  s16[1] * h0v.y);
      p0.y = pack_bf16(s16[2] * h0v.z,  s16[3] * h0v.w);
      p0.z = pack_bf16(s16[4] * h1v.x,  s16[5] * h1v.y);
      p0.w = pack_bf16(s16[6] * h1v.z,  s16[7] * h1v.w);
      p1.x = pack_bf16(s16[8] * h2v.x,  s16[9] * h2v.y);
      p1.y = pack_bf16(s16[10] * h2v.z, s16[11] * h2v.w);
      p1.z = pack_bf16(s16[12] * h3v.x, s16[13] * h3v.y);
      p1.w = pack_bf16(s16[14] * h3v.z, s16[15] * h3v.w);
      *(uint4*)&rhG[idx] = p0;
      *(uint4*)&rhG[idx + 8] = p1;
    } else {
      *(float4*)&ubuf[idx]      = make_float4(s16[0], s16[1], s16[2], s16[3]);
      *(float4*)&ubuf[idx + 4]  = make_float4(s16[4], s16[5], s16[6], s16[7]);
      *(float4*)&ubuf[idx + 8]  = make_float4(s16[8], s16[9], s16[10], s16[11]);
      *(float4*)&ubuf[idx + 12] = make_float4(s16[12], s16[13], s16[14], s16[15]);
    }
  }
}

// k_y2 v2: y2[b][n][o2] = inp[b][n]*W2[0][o2] + sum_h rh[b][n][h]*W2[1+h][o2]
// -> Y2t[b*64+o2][n] bf16, staged in LDS as packed pairs, coalesced uint writes.
// Thread: np=t>>2 owns ADJACENT nodes {2np, 2np+1}; og2=t&3 owns 16 outputs.
__global__ __launch_bounds__(256) void k_y2(const __hip_bfloat16* __restrict__ rhG,
                                            const float* __restrict__ inp,
                                            const float* __restrict__ W2,
                                            __hip_bfloat16* __restrict__ Y2t) {
  __shared__ __align__(16) float W2s[65 * 64];        // 16.6 KB
  __shared__ __align__(16) float rhS[128 * 66];       // 33.8 KB
  __shared__ __align__(16) unsigned y2S[64 * 65];     // 16.6 KB [o2][node_pair]
  __shared__ float inpS[128];
  const int b = blockIdx.x, nt = blockIdx.y;
  const int n0 = nt * 128;
  const int t = threadIdx.x;
  for (int i = t; i < 65 * 64; i += 256) W2s[i] = W2[i];
  for (int i = t; i < 128 * 32; i += 256) {
    const int nl = i >> 5, hp = (i & 31) * 2;
    const unsigned v = *(const unsigned*)&rhG[((size_t)b * NN + n0 + nl) * NH + hp];
    rhS[nl * 66 + hp]     = __uint_as_float((v & 0xffffu) << 16);
    rhS[nl * 66 + hp + 1] = __uint_as_float(v & 0xffff0000u);
  }
  if (t < 128) inpS[t] = inp[(size_t)b * NN + n0 + t];
  __syncthreads();
  const int np = t >> 2, og2 = t & 3;   // np in 0..63 -> nodes 2np, 2np+1
  float acc[2][16];
  {
    const float i0 = inpS[2 * np], i1 = inpS[2 * np + 1];
#pragma unroll
    for (int kq = 0; kq < 4; ++kq) {
      const int kq2 = (kq + og2) & 3;
      const float4 w = *(const float4*)&W2s[og2 * 16 + kq2 * 4];  // W2 row 0 = input weight
      acc[0][kq * 4 + 0] = i0 * w.x;  acc[1][kq * 4 + 0] = i1 * w.x;
      acc[0][kq * 4 + 1] = i0 * w.y;  acc[1][kq * 4 + 1] = i1 * w.y;
      acc[0][kq * 4 + 2] = i0 * w.z;  acc[1][kq * 4 + 2] = i1 * w.z;
      acc[0][kq * 4 + 3] = i0 * w.w;  acc[1][kq * 4 + 3] = i1 * w.w;
    }
  }
  for (int c = 0; c < 64; ++c) {
    const float r0 = rhS[(2 * np) * 66 + c];
    const float r1 = rhS[(2 * np + 1) * 66 + c];
#pragma unroll
    for (int kq = 0; kq < 4; ++kq) {
      const int kq2 = (kq + og2) & 3;
      const float4 w = *(const float4*)&W2s[(c + 1) * 64 + og2 * 16 + kq2 * 4];
      acc[0][kq * 4 + 0] += r0 * w.x;  acc[1][kq * 4 + 0] += r1 * w.x;
      acc[0][kq * 4 + 1] += r0 * w.y;  acc[1][kq * 4 + 1] += r1 * w.y;
      acc[0][kq * 4 + 2] += r0 * w.z;  acc[1][kq * 4 + 2] += r1 * w.z;
      acc[0][kq * 4 + 3] += r0 * w.w;  acc[1][kq * 4 + 3] += r1 * w.w;
    }
  }
  // Stage packed bf16 pairs: y2S[o2][np] = (node 2np, node 2np+1)
#pragma unroll
  for (int kq = 0; kq < 4; ++kq) {
    const int kq2 = (kq + og2) & 3;
#pragma unroll
    for (int j = 0; j < 4; ++j) {
      const int o2 = og2 * 16 + kq2 * 4 + j;
      y2S[o2 * 65 + np] = pack_bf16(acc[0][kq * 4 + j], acc[1][kq * 4 + j]);
    }
  }
  __syncthreads();
  // Coalesced writeback: 64 rows x 64 uints (128 nodes) each.
  for (int i = t; i < 64 * 64; i += 256) {
    const int o2 = i >> 6, npair = i & 63;
    *(unsigned*)&Y2t[(size_t)(b * 64 + o2) * NN + n0 + 2 * npair] = y2S[o2 * 65 + npair];
  }
}

__global__ __launch_bounds__(256) void k_final(const float* __restrict__ cpre,
                                               const float* __restrict__ ubuf,
                                               const float* __restrict__ hid,
                                               const float* __restrict__ b2,
                                               float* __restrict__ out) {
  size_t i4 = (size_t)blockIdx.x * 256 + threadIdx.x;  // 2,097,152 threads
  size_t base = i4 * 4;
  int b = (int)(base / (NN * NH));
  int rem = (int)(base % (NN * NH));
  int n = rem / NH, h0 = rem % NH;
  const float4 u = *(const float4*)&ubuf[base];
  const float4 hv = *(const float4*)&hid[base];
  const size_t ci = (size_t)n * NC2 + b * 64 + h0;
  const float4 cp0 = *(const float4*)&cpre[ci];
  const float4 cp1 = *(const float4*)&cpre[(size_t)NN * NC2 + ci];
  const float4 bb = *(const float4*)&b2[h0];
  float4 r;
  r.x = u.x * hv.x + (1.f - u.x) * tanhf(cp0.x + cp1.x + bb.x);
  r.y = u.y * hv.y + (1.f - u.y) * tanhf(cp0.y + cp1.y + bb.y);
  r.z = u.z * hv.z + (1.f - u.z) * tanhf(cp0.z + cp1.z + bb.z);
  r.w = u.w * hv.w + (1.f - u.w) * tanhf(cp0.w + cp1.w + bb.w);
  *(float4*)&out[base] = r;
}

extern "C" void kernel_launch(void* const* d_in, const int* in_sizes, int n_in,
                              void* d_out, int out_size, void* d_ws, size_t ws_size,
                              hipStream_t stream) {
  const float* inp = (const float*)d_in[0];
  const float* hid = (const float*)d_in[1];
  const float* adj = (const float*)d_in[2];
  const float* W1  = (const float*)d_in[3];
  const float* b1  = (const float*)d_in[4];
  const float* W2  = (const float*)d_in[5];
  const float* b2  = (const float*)d_in[6];
  float* out = (float*)d_out;

  char* w = (char*)d_ws;
  float* dd            = (float*)w;                       w += 8192;
  __hip_bfloat16* Abf  = (__hip_bfloat16*)w;              w += (size_t)NN * NN * 2;            // 8.39 MB
  __hip_bfloat16* X1t  = (__hip_bfloat16*)w;              w += (size_t)NC1P * NN * 2;          // 17.3 MB
  float* ax1           = (float*)w;                       w += (size_t)2 * NN * NC1P * 4;      // 69.2 MB (2 split-K partials)
  __hip_bfloat16* Y2t  = (__hip_bfloat16*)w;              w += (size_t)NC2 * NN * 2;           // 16.8 MB
  float* ubuf          = (float*)w;                       w += (size_t)NB * NN * NH * 4;       // 33.6 MB
  float* cpre          = ax1;                 // ax1 dead after k_out1; 2x33.5MB fits in 69.2
  __hip_bfloat16* rhG  = X1t;                 // X1t dead after GEMM1 (16.78 MB <= 17.3 MB)

  k_deg<<<NN, 256, 0, stream>>>(adj, dd);
  k_buildA<<<dim3(32, 32), 256, 0, stream>>>(adj, dd, Abf);
  k_buildX1<<<dim3(NB, 32), 256, 0, stream>>>(inp, hid, X1t);
  k_zeropad<<<512, 256, 0, stream>>>(X1t);
  k_gemm_bt<<<dim3(16, 33, 2), 256, 0, stream>>>(Abf, X1t, ax1, NC1P, NN / 2);
  k_out1<<<dim3(NB, 16), 256, 0, stream>>>(ax1, W1, b1, hid, rhG, ubuf);
  k_y2<<<dim3(NB, 16), 256, 0, stream>>>(rhG, inp, W2, Y2t);
  k_gemm_bt<<<dim3(16, 32, 2), 256, 0, stream>>>(Abf, Y2t, cpre, NC2, NN / 2);
  k_final<<<8192, 256, 0, stream>>>(cpre, ubuf, hid, b2, out);
}

// Round 11
// 314.233 us; speedup vs baseline: 1.1046x; 1.0472x over previous
//
#include <hip/hip_runtime.h>
#include <hip/hip_bf16.h>

// GCN-GRU cell, MI355X. Sizes fixed per reference: B=64, N=2048, H=64.
// Pipeline:
//  1. k_deg      : d[m] = rsqrt(rowsum(adj)+1)
//  2. k_buildA   : A_bf[m][n] = bf16(d[m]*(adj[n][m]+(m==n))*d[n])   (LDS transpose)
//  3. k_buildX1  : X1t[j=b*65+c][n] = bf16(conc[b,n,c]), padded to 4224 rows
//  4. k_zeropad  : zero pad rows 4160..4223
//  5. k_gemm_bt  : ax1[z][m][j] = sum_{n in split z} A_bf[m][n]*X1t[j][n]
//                  SPLIT-K=2, 2-phase double-buffered K-loop (round-10: GEMMs
//                  dropped below 65us each).
//  6. k_out1     : v5 MFMA — out1 = (ax1[0]+ax1[1])@W1 + b1 as a per-block
//                  128x96x128 bf16 MFMA matmul (K=65 padded to 96); sigmoid
//                  epilogue; m<1024 -> rh=sig*h (bf16), else ubuf=sig.
//                  (round-10: VALU version was 65.5us vs 14us VALU floor,
//                   17% bank-conflict tax — matmul-shaped => MFMA.)
//  7. k_y2       : y2 = inp*W2[0,:] + rh@W2[1:,:] -> Y2t (K-major bf16)
//  8. k_gemm_bt  : cpre[z][m][b*64+o] = sum_{n in split z} A_bf[m][n]*Y2t[b*64+o][n]
//  9. k_final    : out = u*h + (1-u)*tanh(cpre[0]+cpre[1] + b2)

typedef __attribute__((ext_vector_type(8))) short short8;
typedef __attribute__((ext_vector_type(4))) float f32x4;

#define NB 64
#define NN 2048
#define NH 64
#define NC1P 4224   // padded 64*65=4160 -> 33*128
#define NC2 4096

__device__ __forceinline__ void gload16(const void* g, void* l) {
  __builtin_amdgcn_global_load_lds((const __attribute__((address_space(1))) void*)g,
                                   (__attribute__((address_space(3))) void*)l, 16, 0, 0);
}

__device__ __forceinline__ unsigned pack_bf16(float a, float b) {
  unsigned ua = __float_as_uint(a), ub = __float_as_uint(b);
  // round-to-nearest-even bf16, matching __float2bfloat16 for normal values
  ua += 0x7fffu + ((ua >> 16) & 1u);
  ub += 0x7fffu + ((ub >> 16) & 1u);
  return (ua >> 16) | (ub & 0xffff0000u);
}

__global__ __launch_bounds__(256) void k_deg(const float* __restrict__ adj,
                                             float* __restrict__ d) {
  __shared__ float red[256];
  int m = blockIdx.x;
  float s = 0.f;
  for (int j = threadIdx.x; j < NN; j += 256) s += adj[(size_t)m * NN + j];
  red[threadIdx.x] = s;
  __syncthreads();
  for (int off = 128; off > 0; off >>= 1) {
    if (threadIdx.x < off) red[threadIdx.x] += red[threadIdx.x + off];
    __syncthreads();
  }
  if (threadIdx.x == 0) {
    float v = rsqrtf(red[0] + 1.0f);
    d[m] = isinf(v) ? 0.f : v;
  }
}

__global__ __launch_bounds__(256) void k_buildA(const float* __restrict__ adj,
                                                const float* __restrict__ d,
                                                __hip_bfloat16* __restrict__ Abf) {
  __shared__ float t[64][65];
  int m0 = blockIdx.x * 64, n0 = blockIdx.y * 64;
  for (int i = threadIdx.x; i < 64 * 64; i += 256) {
    int r = i >> 6, c = i & 63;                   // adj row n0+r, col m0+c
    t[r][c] = adj[(size_t)(n0 + r) * NN + m0 + c];
  }
  __syncthreads();
  for (int i = threadIdx.x; i < 64 * 64; i += 256) {
    int r = i >> 6, c = i & 63;                   // A row m0+r, col n0+c
    int m = m0 + r, n = n0 + c;
    float v = t[c][r] + (m == n ? 1.0f : 0.0f);
    Abf[(size_t)m * NN + n] = __float2bfloat16(d[m] * v * d[n]);
  }
}

__global__ __launch_bounds__(256) void k_buildX1(const float* __restrict__ inp,
                                                 const float* __restrict__ hid,
                                                 __hip_bfloat16* __restrict__ X1t) {
  __shared__ float t[64][65];
  int b = blockIdx.x, n0 = blockIdx.y * 64;
  for (int i = threadIdx.x; i < 64 * 64; i += 256) {
    int r = i >> 6, h = i & 63;
    t[r][h] = hid[((size_t)b * NN + n0 + r) * NH + h];
  }
  __syncthreads();
  for (int i = threadIdx.x; i < 64 * 64; i += 256) {
    int h = i >> 6, r = i & 63;
    X1t[(size_t)(b * 65 + 1 + h) * NN + n0 + r] = __float2bfloat16(t[r][h]);
  }
  if (threadIdx.x < 64) {
    int r = threadIdx.x;
    X1t[(size_t)(b * 65) * NN + n0 + r] = __float2bfloat16(inp[(size_t)b * NN + n0 + r]);
  }
}

__global__ __launch_bounds__(256) void k_zeropad(__hip_bfloat16* __restrict__ X1t) {
  size_t i = (size_t)blockIdx.x * 256 + threadIdx.x;   // 64*2048 elems
  X1t[(size_t)4160 * NN + i] = __float2bfloat16(0.f);
}

// C[z][M x Nc] = A[M x Kslice(z)] * Bt[Nc x Kslice(z)]^T ; bf16 in, f32 out.
// 128x128 tile, BK=32, split-K over blockIdx.z; double-buffered 2-phase K-loop.
__global__ __launch_bounds__(256) void k_gemm_bt(const __hip_bfloat16* __restrict__ Ag,
                                                 const __hip_bfloat16* __restrict__ Bg,
                                                 float* __restrict__ Cg,
                                                 int Ncdim, int Ksplit) {
  __shared__ char lds[32768];   // [2 buffers][A 8KB | B 8KB]
  const int m0 = blockIdx.x * 128, n0 = blockIdx.y * 128;
  const int koff = blockIdx.z * Ksplit;
  Cg += (size_t)blockIdx.z * NN * Ncdim;
  const int tid = threadIdx.x;
  const int wave = tid >> 6, lane = tid & 63;
  const int wr = wave >> 1, wc = wave & 1;
  const size_t strB = (size_t)NN * 2;  // bytes per row (K = NN always)
  const char* ga0 = (const char*)Ag + (size_t)(m0 + wave * 16 + (lane >> 2)) * strB + (lane & 3) * 16;
  const char* gb0 = (const char*)Bg + (size_t)(n0 + wave * 16 + (lane >> 2)) * strB + (lane & 3) * 16;
  const char* ga1 = ga0 + 64 * strB;
  const char* gb1 = gb0 + 64 * strB;
  char* const lw = lds + wave * 1024;   // wave-uniform LDS base; HW adds lane*16
  f32x4 acc[4][4] = {};
  const int rowi = lane & 15;
  const int kb = (lane >> 4) * 16;      // byte offset of k-slice within 64B row

  // prologue: stage tile 0 into buffer 0
  {
    const size_t kb2 = (size_t)koff * 2;
    gload16(ga0 + kb2, lw);
    gload16(ga1 + kb2, lw + 4096);
    gload16(gb0 + kb2, lw + 8192);
    gload16(gb1 + kb2, lw + 12288);
  }
  __syncthreads();
  int cur = 0;
  for (int kk = koff + 32; kk < koff + Ksplit; kk += 32) {
    // phase 1: issue next-tile loads into the other buffer (overlap with compute)
    {
      char* ldst = lw + (cur ^ 1) * 16384;
      const size_t kb2 = (size_t)kk * 2;
      gload16(ga0 + kb2, ldst);
      gload16(ga1 + kb2, ldst + 4096);
      gload16(gb0 + kb2, ldst + 8192);
      gload16(gb1 + kb2, ldst + 12288);
    }
    // phase 2: compute current buffer
    const char* lA = lds + cur * 16384;
    const char* lB = lA + 8192;
    short8 af[4], bfr[4];
#pragma unroll
    for (int f = 0; f < 4; ++f) {
      af[f]  = *(const short8*)(lA + (wr * 64 + f * 16 + rowi) * 64 + kb);
      bfr[f] = *(const short8*)(lB + (wc * 64 + f * 16 + rowi) * 64 + kb);
    }
#pragma unroll
    for (int i = 0; i < 4; ++i)
#pragma unroll
      for (int j = 0; j < 4; ++j)
        acc[i][j] = __builtin_amdgcn_mfma_f32_16x16x32_bf16(af[i], bfr[j], acc[i][j], 0, 0, 0);
    __syncthreads();   // drains next-tile loads (vmcnt) + this-tile reads (lgkm)
    cur ^= 1;
  }
  // epilogue: last tile already staged
  {
    const char* lA = lds + cur * 16384;
    const char* lB = lA + 8192;
    short8 af[4], bfr[4];
#pragma unroll
    for (int f = 0; f < 4; ++f) {
      af[f]  = *(const short8*)(lA + (wr * 64 + f * 16 + rowi) * 64 + kb);
      bfr[f] = *(const short8*)(lB + (wc * 64 + f * 16 + rowi) * 64 + kb);
    }
#pragma unroll
    for (int i = 0; i < 4; ++i)
#pragma unroll
      for (int j = 0; j < 4; ++j)
        acc[i][j] = __builtin_amdgcn_mfma_f32_16x16x32_bf16(af[i], bfr[j], acc[i][j], 0, 0, 0);
  }
  const int cn = n0 + wc * 64 + (lane & 15);
  const int rb = m0 + wr * 64 + ((lane >> 4) << 2);
#pragma unroll
  for (int i = 0; i < 4; ++i)
#pragma unroll
    for (int j = 0; j < 4; ++j)
#pragma unroll
      for (int r = 0; r < 4; ++r)
        Cg[(size_t)(rb + i * 16 + r) * Ncdim + (cn + j * 16)] = acc[i][j][r];
}

// k_out1 v5 (MFMA): per block (b, mt): out1[128 rows][128 outs] =
//   bf16(ax1[0]+ax1[1])[128][K=65 pad 96] @ bf16(W1^T)[128][96] + b1, sigmoid.
// mt<8 (m<1024): rh[b][2m+s][h] = sig*hid (bf16); mt>=8: ubuf = sig.
// Fragment/acc layout identical to k_gemm_bt (4-wave 64x64 quadrants).
// Row stride 104 bf16 = 208B: 16B-aligned rows, minimal bank aliasing.
__global__ __launch_bounds__(256) void k_out1(const float* __restrict__ ax1,
                                              const float* __restrict__ W1,
                                              const float* __restrict__ b1,
                                              const float* __restrict__ hid,
                                              __hip_bfloat16* __restrict__ rhG,
                                              float* __restrict__ ubuf) {
  __shared__ __align__(16) __hip_bfloat16 aT[128 * 104];   // 26.6 KB [m_local][k]
  __shared__ __align__(16) __hip_bfloat16 wT[128 * 104];   // 26.6 KB [o][k]
  __shared__ float b1S[128];
  const int b = blockIdx.x, mt = blockIdx.y;      // mt 0..15; <8 -> rh, >=8 -> u
  const bool isRH = (mt < 8);
  const int mh0 = (mt & 7) * 128;                 // row offset within half
  const int mabs0 = (isRH ? 0 : 1024) + mh0;      // ax1 absolute row
  const int t = threadIdx.x;
  const float* __restrict__ ax1b = ax1 + (size_t)NN * NC1P;   // split-K partial 1
  // stage W1^T (o-major, k-contiguous) as bf16; zero-pad k=65..95
  for (int i = t; i < 65 * 128; i += 256) {
    const int c = i >> 7, o = i & 127;
    wT[o * 104 + c] = __float2bfloat16(W1[i]);
  }
  for (int i = t; i < 31 * 128; i += 256) {
    const int c = 65 + (i >> 7), o = i & 127;
    wT[o * 104 + c] = __float2bfloat16(0.f);
  }
  if (t < 128) b1S[t] = b1[t];
  // stage summed split-K partials as bf16; zero-pad k=65..95
  for (int i = t; i < 128 * 65; i += 256) {
    const int r = i / 65, c = i - r * 65;
    const size_t gi = (size_t)(mabs0 + r) * NC1P + b * 65 + c;
    aT[r * 104 + c] = __float2bfloat16(ax1[gi] + ax1b[gi]);
  }
  for (int i = t; i < 128 * 31; i += 256) {
    const int r = i / 31, c = 65 + (i - r * 31);
    aT[r * 104 + c] = __float2bfloat16(0.f);
  }
  __syncthreads();
  const int wave = t >> 6, lane = t & 63;
  const int wr = wave >> 1, wc = wave & 1;
  const int rowi = lane & 15;
  const int kb = (lane >> 4) * 8;                 // bf16 offset within 32-wide k-slice
  f32x4 acc[4][4] = {};
#pragma unroll
  for (int ks = 0; ks < 3; ++ks) {
    short8 af[4], bfr[4];
#pragma unroll
    for (int f = 0; f < 4; ++f) {
      af[f]  = *(const short8*)&aT[(wr * 64 + f * 16 + rowi) * 104 + ks * 32 + kb];
      bfr[f] = *(const short8*)&wT[(wc * 64 + f * 16 + rowi) * 104 + ks * 32 + kb];
    }
#pragma unroll
    for (int i = 0; i < 4; ++i)
#pragma unroll
      for (int j = 0; j < 4; ++j)
        acc[i][j] = __builtin_amdgcn_mfma_f32_16x16x32_bf16(af[i], bfr[j], acc[i][j], 0, 0, 0);
  }
  // epilogue: bias + sigmoid + scatter (16-lane groups -> contiguous h runs)
  const int hb = lane & 15;                       // h base within 64
  const int rb = wr * 64 + ((lane >> 4) << 2);    // m-local row base
#pragma unroll
  for (int i = 0; i < 4; ++i) {
#pragma unroll
    for (int r = 0; r < 4; ++r) {
      const int row = rb + i * 16 + r;            // m-local 0..127
      const int n = 2 * (mh0 + row) + wc;         // node index
      const size_t base = ((size_t)b * NN + n) * NH;
      if (isRH) {
#pragma unroll
        for (int j = 0; j < 4; ++j) {
          const int h = hb + j * 16;
          const float v = acc[i][j][r] + b1S[wc * 64 + h];
          const float sig = 1.0f / (1.0f + __expf(-v));
          rhG[base + h] = __float2bfloat16(sig * hid[base + h]);
        }
      } else {
#pragma unroll
        for (int j = 0; j < 4; ++j) {
          const int h = hb + j * 16;
          const float v = acc[i][j][r] + b1S[wc * 64 + h];
          ubuf[base + h] = 1.0f / (1.0f + __expf(-v));
        }
      }
    }
  }
}

// k_y2 v2: y2[b][n][o2] = inp[b][n]*W2[0][o2] + sum_h rh[b][n][h]*W2[1+h][o2]
// -> Y2t[b*64+o2][n] bf16, staged in LDS as packed pairs, coalesced uint writes.
// Thread: np=t>>2 owns ADJACENT nodes {2np, 2np+1}; og2=t&3 owns 16 outputs.
__global__ __launch_bounds__(256) void k_y2(const __hip_bfloat16* __restrict__ rhG,
                                            const float* __restrict__ inp,
                                            const float* __restrict__ W2,
                                            __hip_bfloat16* __restrict__ Y2t) {
  __shared__ __align__(16) float W2s[65 * 64];        // 16.6 KB
  __shared__ __align__(16) float rhS[128 * 66];       // 33.8 KB
  __shared__ __align__(16) unsigned y2S[64 * 65];     // 16.6 KB [o2][node_pair]
  __shared__ float inpS[128];
  const int b = blockIdx.x, nt = blockIdx.y;
  const int n0 = nt * 128;
  const int t = threadIdx.x;
  for (int i = t; i < 65 * 64; i += 256) W2s[i] = W2[i];
  for (int i = t; i < 128 * 32; i += 256) {
    const int nl = i >> 5, hp = (i & 31) * 2;
    const unsigned v = *(const unsigned*)&rhG[((size_t)b * NN + n0 + nl) * NH + hp];
    rhS[nl * 66 + hp]     = __uint_as_float((v & 0xffffu) << 16);
    rhS[nl * 66 + hp + 1] = __uint_as_float(v & 0xffff0000u);
  }
  if (t < 128) inpS[t] = inp[(size_t)b * NN + n0 + t];
  __syncthreads();
  const int np = t >> 2, og2 = t & 3;   // np in 0..63 -> nodes 2np, 2np+1
  float acc[2][16];
  {
    const float i0 = inpS[2 * np], i1 = inpS[2 * np + 1];
#pragma unroll
    for (int kq = 0; kq < 4; ++kq) {
      const int kq2 = (kq + og2) & 3;
      const float4 w = *(const float4*)&W2s[og2 * 16 + kq2 * 4];  // W2 row 0 = input weight
      acc[0][kq * 4 + 0] = i0 * w.x;  acc[1][kq * 4 + 0] = i1 * w.x;
      acc[0][kq * 4 + 1] = i0 * w.y;  acc[1][kq * 4 + 1] = i1 * w.y;
      acc[0][kq * 4 + 2] = i0 * w.z;  acc[1][kq * 4 + 2] = i1 * w.z;
      acc[0][kq * 4 + 3] = i0 * w.w;  acc[1][kq * 4 + 3] = i1 * w.w;
    }
  }
  for (int c = 0; c < 64; ++c) {
    const float r0 = rhS[(2 * np) * 66 + c];
    const float r1 = rhS[(2 * np + 1) * 66 + c];
#pragma unroll
    for (int kq = 0; kq < 4; ++kq) {
      const int kq2 = (kq + og2) & 3;
      const float4 w = *(const float4*)&W2s[(c + 1) * 64 + og2 * 16 + kq2 * 4];
      acc[0][kq * 4 + 0] += r0 * w.x;  acc[1][kq * 4 + 0] += r1 * w.x;
      acc[0][kq * 4 + 1] += r0 * w.y;  acc[1][kq * 4 + 1] += r1 * w.y;
      acc[0][kq * 4 + 2] += r0 * w.z;  acc[1][kq * 4 + 2] += r1 * w.z;
      acc[0][kq * 4 + 3] += r0 * w.w;  acc[1][kq * 4 + 3] += r1 * w.w;
    }
  }
  // Stage packed bf16 pairs: y2S[o2][np] = (node 2np, node 2np+1)
#pragma unroll
  for (int kq = 0; kq < 4; ++kq) {
    const int kq2 = (kq + og2) & 3;
#pragma unroll
    for (int j = 0; j < 4; ++j) {
      const int o2 = og2 * 16 + kq2 * 4 + j;
      y2S[o2 * 65 + np] = pack_bf16(acc[0][kq * 4 + j], acc[1][kq * 4 + j]);
    }
  }
  __syncthreads();
  // Coalesced writeback: 64 rows x 64 uints (128 nodes) each.
  for (int i = t; i < 64 * 64; i += 256) {
    const int o2 = i >> 6, npair = i & 63;
    *(unsigned*)&Y2t[(size_t)(b * 64 + o2) * NN + n0 + 2 * npair] = y2S[o2 * 65 + npair];
  }
}

__global__ __launch_bounds__(256) void k_final(const float* __restrict__ cpre,
                                               const float* __restrict__ ubuf,
                                               const float* __restrict__ hid,
                                               const float* __restrict__ b2,
                                               float* __restrict__ out) {
  size_t i4 = (size_t)blockIdx.x * 256 + threadIdx.x;  // 2,097,152 threads
  size_t base = i4 * 4;
  int b = (int)(base / (NN * NH));
  int rem = (int)(base % (NN * NH));
  int n = rem / NH, h0 = rem % NH;
  const float4 u = *(const float4*)&ubuf[base];
  const float4 hv = *(const float4*)&hid[base];
  const size_t ci = (size_t)n * NC2 + b * 64 + h0;
  const float4 cp0 = *(const float4*)&cpre[ci];
  const float4 cp1 = *(const float4*)&cpre[(size_t)NN * NC2 + ci];
  const float4 bb = *(const float4*)&b2[h0];
  float4 r;
  r.x = u.x * hv.x + (1.f - u.x) * tanhf(cp0.x + cp1.x + bb.x);
  r.y = u.y * hv.y + (1.f - u.y) * tanhf(cp0.y + cp1.y + bb.y);
  r.z = u.z * hv.z + (1.f - u.z) * tanhf(cp0.z + cp1.z + bb.z);
  r.w = u.w * hv.w + (1.f - u.w) * tanhf(cp0.w + cp1.w + bb.w);
  *(float4*)&out[base] = r;
}

extern "C" void kernel_launch(void* const* d_in, const int* in_sizes, int n_in,
                              void* d_out, int out_size, void* d_ws, size_t ws_size,
                              hipStream_t stream) {
  const float* inp = (const float*)d_in[0];
  const float* hid = (const float*)d_in[1];
  const float* adj = (const float*)d_in[2];
  const float* W1  = (const float*)d_in[3];
  const float* b1  = (const float*)d_in[4];
  const float* W2  = (const float*)d_in[5];
  const float* b2  = (const float*)d_in[6];
  float* out = (float*)d_out;

  char* w = (char*)d_ws;
  float* dd            = (float*)w;                       w += 8192;
  __hip_bfloat16* Abf  = (__hip_bfloat16*)w;              w += (size_t)NN * NN * 2;            // 8.39 MB
  __hip_bfloat16* X1t  = (__hip_bfloat16*)w;              w += (size_t)NC1P * NN * 2;          // 17.3 MB
  float* ax1           = (float*)w;                       w += (size_t)2 * NN * NC1P * 4;      // 69.2 MB (2 split-K partials)
  __hip_bfloat16* Y2t  = (__hip_bfloat16*)w;              w += (size_t)NC2 * NN * 2;           // 16.8 MB
  float* ubuf          = (float*)w;                       w += (size_t)NB * NN * NH * 4;       // 33.6 MB
  float* cpre          = ax1;                 // ax1 dead after k_out1; 2x33.5MB fits in 69.2
  __hip_bfloat16* rhG  = X1t;                 // X1t dead after GEMM1 (16.78 MB <= 17.3 MB)

  k_deg<<<NN, 256, 0, stream>>>(adj, dd);
  k_buildA<<<dim3(32, 32), 256, 0, stream>>>(adj, dd, Abf);
  k_buildX1<<<dim3(NB, 32), 256, 0, stream>>>(inp, hid, X1t);
  k_zeropad<<<512, 256, 0, stream>>>(X1t);
  k_gemm_bt<<<dim3(16, 33, 2), 256, 0, stream>>>(Abf, X1t, ax1, NC1P, NN / 2);
  k_out1<<<dim3(NB, 16), 256, 0, stream>>>(ax1, W1, b1, hid, rhG, ubuf);
  k_y2<<<dim3(NB, 16), 256, 0, stream>>>(rhG, inp, W2, Y2t);
  k_gemm_bt<<<dim3(16, 32, 2), 256, 0, stream>>>(Abf, Y2t, cpre, NC2, NN / 2);
  k_final<<<8192, 256, 0, stream>>>(cpre, ubuf, hid, b2, out);
}

// Round 13
// 304.448 us; speedup vs baseline: 1.1401x; 1.0321x over previous
//
#include <hip/hip_runtime.h>
#include <hip/hip_bf16.h>

// GCN-GRU cell, MI355X. Sizes fixed per reference: B=64, N=2048, H=64.
// Pipeline:
//  1. k_deg      : d[m] = rsqrt(rowsum(adj)+1)
//  2. k_buildA   : A_bf[m][n] = bf16(d[m]*(adj[n][m]+(m==n))*d[n])   (LDS transpose)
//  3. k_buildX1  : X1t[j=b*65+c][n] = bf16(conc[b,n,c]), padded to 4224 rows
//  4. k_zeropad  : zero pad rows 4160..4223
//  5. k_gemm_bt<true>  : ax1bf[z][m][j] = bf16( sum_{n in split z} A_bf[m][n]*X1t[j][n] )
//                  split-K=2, 2-phase dbuf K-loop, XCD-aware bijective block swizzle
//                  (round-11: FETCH 74MB vs 26 ideal — B replicated across all 8 XCD L2s;
//                   GEMM1 f32 out was immediately bf16-converted by k_out1 anyway).
//  6. k_out1     : aT = bf16(ax1bf[0]+ax1bf[1]); MFMA out1 = aT@W1+b1; sigmoid;
//                  m<1024 -> rh=sig*h (bf16), m>=1024 -> ubuf=sig
//  7. k_y2       : y2 = inp*W2[0,:] + rh@W2[1:,:] -> Y2t (K-major bf16)
//  8. k_gemm_bt<false> : cpre[z][m][b*64+o] (f32, tanh-path precision)
//  9. k_final    : out = u*h + (1-u)*tanh(cpre[0]+cpre[1] + b2)

typedef __attribute__((ext_vector_type(8))) short short8;
typedef __attribute__((ext_vector_type(4))) float f32x4;

#define NB 64
#define NN 2048
#define NH 64
#define NC1P 4224   // padded 64*65=4160 -> 33*128
#define NC2 4096

__device__ __forceinline__ void gload16(const void* g, void* l) {
  __builtin_amdgcn_global_load_lds((const __attribute__((address_space(1))) void*)g,
                                   (__attribute__((address_space(3))) void*)l, 16, 0, 0);
}

__device__ __forceinline__ unsigned pack_bf16(float a, float b) {
  unsigned ua = __float_as_uint(a), ub = __float_as_uint(b);
  // round-to-nearest-even bf16, matching __float2bfloat16 for normal values
  ua += 0x7fffu + ((ua >> 16) & 1u);
  ub += 0x7fffu + ((ub >> 16) & 1u);
  return (ua >> 16) | (ub & 0xffff0000u);
}

__global__ __launch_bounds__(256) void k_deg(const float* __restrict__ adj,
                                             float* __restrict__ d) {
  __shared__ float red[256];
  int m = blockIdx.x;
  float s = 0.f;
  for (int j = threadIdx.x; j < NN; j += 256) s += adj[(size_t)m * NN + j];
  red[threadIdx.x] = s;
  __syncthreads();
  for (int off = 128; off > 0; off >>= 1) {
    if (threadIdx.x < off) red[threadIdx.x] += red[threadIdx.x + off];
    __syncthreads();
  }
  if (threadIdx.x == 0) {
    float v = rsqrtf(red[0] + 1.0f);
    d[m] = isinf(v) ? 0.f : v;
  }
}

__global__ __launch_bounds__(256) void k_buildA(const float* __restrict__ adj,
                                                const float* __restrict__ d,
                                                __hip_bfloat16* __restrict__ Abf) {
  __shared__ float t[64][65];
  int m0 = blockIdx.x * 64, n0 = blockIdx.y * 64;
  for (int i = threadIdx.x; i < 64 * 64; i += 256) {
    int r = i >> 6, c = i & 63;                   // adj row n0+r, col m0+c
    t[r][c] = adj[(size_t)(n0 + r) * NN + m0 + c];
  }
  __syncthreads();
  for (int i = threadIdx.x; i < 64 * 64; i += 256) {
    int r = i >> 6, c = i & 63;                   // A row m0+r, col n0+c
    int m = m0 + r, n = n0 + c;
    float v = t[c][r] + (m == n ? 1.0f : 0.0f);
    Abf[(size_t)m * NN + n] = __float2bfloat16(d[m] * v * d[n]);
  }
}

__global__ __launch_bounds__(256) void k_buildX1(const float* __restrict__ inp,
                                                 const float* __restrict__ hid,
                                                 __hip_bfloat16* __restrict__ X1t) {
  __shared__ float t[64][65];
  int b = blockIdx.x, n0 = blockIdx.y * 64;
  for (int i = threadIdx.x; i < 64 * 64; i += 256) {
    int r = i >> 6, h = i & 63;
    t[r][h] = hid[((size_t)b * NN + n0 + r) * NH + h];
  }
  __syncthreads();
  for (int i = threadIdx.x; i < 64 * 64; i += 256) {
    int h = i >> 6, r = i & 63;
    X1t[(size_t)(b * 65 + 1 + h) * NN + n0 + r] = __float2bfloat16(t[r][h]);
  }
  if (threadIdx.x < 64) {
    int r = threadIdx.x;
    X1t[(size_t)(b * 65) * NN + n0 + r] = __float2bfloat16(inp[(size_t)b * NN + n0 + r]);
  }
}

__global__ __launch_bounds__(256) void k_zeropad(__hip_bfloat16* __restrict__ X1t) {
  size_t i = (size_t)blockIdx.x * 256 + threadIdx.x;   // 64*2048 elems
  X1t[(size_t)4160 * NN + i] = __float2bfloat16(0.f);
}

// C[z][M x Nc] = A[M x Kslice(z)] * Bt[Nc x Kslice(z)]^T ; bf16 in.
// BF16OUT: bf16 C (GEMM1 -> consumer converts to bf16 anyway); else f32.
// 128x128 tile, BK=32, split-K over z; double-buffered 2-phase K-loop.
// XCD-aware bijective swizzle: XCD k owns nwg/8 consecutive tiles (m-fastest),
// so each XCD's L2 holds its own ~4MB slice of B instead of all 8 replicating it.
template <bool BF16OUT>
__global__ __launch_bounds__(256) void k_gemm_bt(const __hip_bfloat16* __restrict__ Ag,
                                                 const __hip_bfloat16* __restrict__ Bg,
                                                 void* __restrict__ Cg_,
                                                 int Ncdim, int Ksplit) {
  __shared__ char lds[32768];   // [2 buffers][A 8KB | B 8KB]
  // ---- bijective XCD remap (nwg = 1056 or 1024, both % 8 == 0) ----
  const int nx = 16;
  const int ny = Ncdim >> 7;
  const int lin = blockIdx.x + nx * (blockIdx.y + ny * blockIdx.z);
  const int cpx = (nx * ny * 2) >> 3;
  const int swz = (lin & 7) * cpx + (lin >> 3);
  const int bx = swz & 15;            // swz % 16
  const int rest = swz >> 4;
  const int by = rest % ny;
  const int bz = rest / ny;
  // -----------------------------------------------------------------
  const int m0 = bx * 128, n0 = by * 128;
  const int koff = bz * Ksplit;
  const int tid = threadIdx.x;
  const int wave = tid >> 6, lane = tid & 63;
  const int wr = wave >> 1, wc = wave & 1;
  const size_t strB = (size_t)NN * 2;  // bytes per row (K = NN always)
  const char* ga0 = (const char*)Ag + (size_t)(m0 + wave * 16 + (lane >> 2)) * strB + (lane & 3) * 16;
  const char* gb0 = (const char*)Bg + (size_t)(n0 + wave * 16 + (lane >> 2)) * strB + (lane & 3) * 16;
  const char* ga1 = ga0 + 64 * strB;
  const char* gb1 = gb0 + 64 * strB;
  char* const lw = lds + wave * 1024;   // wave-uniform LDS base; HW adds lane*16
  f32x4 acc[4][4] = {};
  const int rowi = lane & 15;
  const int kb = (lane >> 4) * 16;      // byte offset of k-slice within 64B row

  // prologue: stage tile 0 into buffer 0
  {
    const size_t kb2 = (size_t)koff * 2;
    gload16(ga0 + kb2, lw);
    gload16(ga1 + kb2, lw + 4096);
    gload16(gb0 + kb2, lw + 8192);
    gload16(gb1 + kb2, lw + 12288);
  }
  __syncthreads();
  int cur = 0;
  for (int kk = koff + 32; kk < koff + Ksplit; kk += 32) {
    // phase 1: issue next-tile loads into the other buffer (overlap with compute)
    {
      char* ldst = lw + (cur ^ 1) * 16384;
      const size_t kb2 = (size_t)kk * 2;
      gload16(ga0 + kb2, ldst);
      gload16(ga1 + kb2, ldst + 4096);
      gload16(gb0 + kb2, ldst + 8192);
      gload16(gb1 + kb2, ldst + 12288);
    }
    // phase 2: compute current buffer
    const char* lA = lds + cur * 16384;
    const char* lB = lA + 8192;
    short8 af[4], bfr[4];
#pragma unroll
    for (int f = 0; f < 4; ++f) {
      af[f]  = *(const short8*)(lA + (wr * 64 + f * 16 + rowi) * 64 + kb);
      bfr[f] = *(const short8*)(lB + (wc * 64 + f * 16 + rowi) * 64 + kb);
    }
#pragma unroll
    for (int i = 0; i < 4; ++i)
#pragma unroll
      for (int j = 0; j < 4; ++j)
        acc[i][j] = __builtin_amdgcn_mfma_f32_16x16x32_bf16(af[i], bfr[j], acc[i][j], 0, 0, 0);
    __syncthreads();   // drains next-tile loads (vmcnt) + this-tile reads (lgkm)
    cur ^= 1;
  }
  // epilogue: last tile already staged
  {
    const char* lA = lds + cur * 16384;
    const char* lB = lA + 8192;
    short8 af[4], bfr[4];
#pragma unroll
    for (int f = 0; f < 4; ++f) {
      af[f]  = *(const short8*)(lA + (wr * 64 + f * 16 + rowi) * 64 + kb);
      bfr[f] = *(const short8*)(lB + (wc * 64 + f * 16 + rowi) * 64 + kb);
    }
#pragma unroll
    for (int i = 0; i < 4; ++i)
#pragma unroll
      for (int j = 0; j < 4; ++j)
        acc[i][j] = __builtin_amdgcn_mfma_f32_16x16x32_bf16(af[i], bfr[j], acc[i][j], 0, 0, 0);
  }
  const int cn = n0 + wc * 64 + (lane & 15);
  const int rb = m0 + wr * 64 + ((lane >> 4) << 2);
  if constexpr (BF16OUT) {
    __hip_bfloat16* C = (__hip_bfloat16*)Cg_ + (size_t)bz * NN * Ncdim;
#pragma unroll
    for (int i = 0; i < 4; ++i)
#pragma unroll
      for (int j = 0; j < 4; ++j)
#pragma unroll
        for (int r = 0; r < 4; ++r)
          C[(size_t)(rb + i * 16 + r) * Ncdim + (cn + j * 16)] = __float2bfloat16(acc[i][j][r]);
  } else {
    float* C = (float*)Cg_ + (size_t)bz * NN * Ncdim;
#pragma unroll
    for (int i = 0; i < 4; ++i)
#pragma unroll
      for (int j = 0; j < 4; ++j)
#pragma unroll
        for (int r = 0; r < 4; ++r)
          C[(size_t)(rb + i * 16 + r) * Ncdim + (cn + j * 16)] = acc[i][j][r];
  }
}

// k_out1 v6 (MFMA, bf16 partial input): per block (b, mt):
//   out1[128 rows][128 outs] = bf16(ax1[0]+ax1[1])[128][K=65 pad 96] @ bf16(W1^T)[128][96]
//   + b1, sigmoid. mt<8 (m<1024): rh = sig*hid (bf16); mt>=8: ubuf = sig.
// Fragment/acc layout identical to k_gemm_bt (4-wave 64x64 quadrants).
__global__ __launch_bounds__(256) void k_out1(const __hip_bfloat16* __restrict__ ax1,
                                              const float* __restrict__ W1,
                                              const float* __restrict__ b1,
                                              const float* __restrict__ hid,
                                              __hip_bfloat16* __restrict__ rhG,
                                              float* __restrict__ ubuf) {
  __shared__ __align__(16) __hip_bfloat16 aT[128 * 104];   // 26.6 KB [m_local][k]
  __shared__ __align__(16) __hip_bfloat16 wT[128 * 104];   // 26.6 KB [o][k]
  __shared__ float b1S[128];
  const int b = blockIdx.x, mt = blockIdx.y;      // mt 0..15; <8 -> rh, >=8 -> u
  const bool isRH = (mt < 8);
  const int mh0 = (mt & 7) * 128;                 // row offset within half
  const int mabs0 = (isRH ? 0 : 1024) + mh0;      // ax1 absolute row
  const int t = threadIdx.x;
  const __hip_bfloat16* __restrict__ ax1b = ax1 + (size_t)NN * NC1P;   // split-K partial 1
  // stage W1^T (o-major, k-contiguous) as bf16; zero-pad k=65..95
  for (int i = t; i < 65 * 128; i += 256) {
    const int c = i >> 7, o = i & 127;
    wT[o * 104 + c] = __float2bfloat16(W1[i]);
  }
  for (int i = t; i < 31 * 128; i += 256) {
    const int c = 65 + (i >> 7), o = i & 127;
    wT[o * 104 + c] = __float2bfloat16(0.f);
  }
  if (t < 128) b1S[t] = b1[t];
  // stage summed split-K partials (bf16 in, f32 add, bf16 out); zero-pad k=65..95
  for (int i = t; i < 128 * 65; i += 256) {
    const int r = i / 65, c = i - r * 65;
    const size_t gi = (size_t)(mabs0 + r) * NC1P + b * 65 + c;
    aT[r * 104 + c] =
        __float2bfloat16(__bfloat162float(ax1[gi]) + __bfloat162float(ax1b[gi]));
  }
  for (int i = t; i < 128 * 31; i += 256) {
    const int r = i / 31, c = 65 + (i - r * 31);
    aT[r * 104 + c] = __float2bfloat16(0.f);
  }
  __syncthreads();
  const int wave = t >> 6, lane = t & 63;
  const int wr = wave >> 1, wc = wave & 1;
  const int rowi = lane & 15;
  const int kb = (lane >> 4) * 8;                 // bf16 offset within 32-wide k-slice
  f32x4 acc[4][4] = {};
#pragma unroll
  for (int ks = 0; ks < 3; ++ks) {
    short8 af[4], bfr[4];
#pragma unroll
    for (int f = 0; f < 4; ++f) {
      af[f]  = *(const short8*)&aT[(wr * 64 + f * 16 + rowi) * 104 + ks * 32 + kb];
      bfr[f] = *(const short8*)&wT[(wc * 64 + f * 16 + rowi) * 104 + ks * 32 + kb];
    }
#pragma unroll
    for (int i = 0; i < 4; ++i)
#pragma unroll
      for (int j = 0; j < 4; ++j)
        acc[i][j] = __builtin_amdgcn_mfma_f32_16x16x32_bf16(af[i], bfr[j], acc[i][j], 0, 0, 0);
  }
  // epilogue: bias + sigmoid + scatter (16-lane groups -> contiguous h runs)
  const int hb = lane & 15;                       // h base within 64
  const int rb = wr * 64 + ((lane >> 4) << 2);    // m-local row base
#pragma unroll
  for (int i = 0; i < 4; ++i) {
#pragma unroll
    for (int r = 0; r < 4; ++r) {
      const int row = rb + i * 16 + r;            // m-local 0..127
      const int n = 2 * (mh0 + row) + wc;         // node index
      const size_t base = ((size_t)b * NN + n) * NH;
      if (isRH) {
#pragma unroll
        for (int j = 0; j < 4; ++j) {
          const int h = hb + j * 16;
          const float v = acc[i][j][r] + b1S[wc * 64 + h];
          const float sig = 1.0f / (1.0f + __expf(-v));
          rhG[base + h] = __float2bfloat16(sig * hid[base + h]);
        }
      } else {
#pragma unroll
        for (int j = 0; j < 4; ++j) {
          const int h = hb + j * 16;
          const float v = acc[i][j][r] + b1S[wc * 64 + h];
          ubuf[base + h] = 1.0f / (1.0f + __expf(-v));
        }
      }
    }
  }
}

// k_y2 v2: y2[b][n][o2] = inp[b][n]*W2[0][o2] + sum_h rh[b][n][h]*W2[1+h][o2]
// -> Y2t[b*64+o2][n] bf16, staged in LDS as packed pairs, coalesced uint writes.
// Thread: np=t>>2 owns ADJACENT nodes {2np, 2np+1}; og2=t&3 owns 16 outputs.
__global__ __launch_bounds__(256) void k_y2(const __hip_bfloat16* __restrict__ rhG,
                                            const float* __restrict__ inp,
                                            const float* __restrict__ W2,
                                            __hip_bfloat16* __restrict__ Y2t) {
  __shared__ __align__(16) float W2s[65 * 64];        // 16.6 KB
  __shared__ __align__(16) float rhS[128 * 66];       // 33.8 KB
  __shared__ __align__(16) unsigned y2S[64 * 65];     // 16.6 KB [o2][node_pair]
  __shared__ float inpS[128];
  const int b = blockIdx.x, nt = blockIdx.y;
  const int n0 = nt * 128;
  const int t = threadIdx.x;
  for (int i = t; i < 65 * 64; i += 256) W2s[i] = W2[i];
  for (int i = t; i < 128 * 32; i += 256) {
    const int nl = i >> 5, hp = (i & 31) * 2;
    const unsigned v = *(const unsigned*)&rhG[((size_t)b * NN + n0 + nl) * NH + hp];
    rhS[nl * 66 + hp]     = __uint_as_float((v & 0xffffu) << 16);
    rhS[nl * 66 + hp + 1] = __uint_as_float(v & 0xffff0000u);
  }
  if (t < 128) inpS[t] = inp[(size_t)b * NN + n0 + t];
  __syncthreads();
  const int np = t >> 2, og2 = t & 3;   // np in 0..63 -> nodes 2np, 2np+1
  float acc[2][16];
  {
    const float i0 = inpS[2 * np], i1 = inpS[2 * np + 1];
#pragma unroll
    for (int kq = 0; kq < 4; ++kq) {
      const int kq2 = (kq + og2) & 3;
      const float4 w = *(const float4*)&W2s[og2 * 16 + kq2 * 4];  // W2 row 0 = input weight
      acc[0][kq * 4 + 0] = i0 * w.x;  acc[1][kq * 4 + 0] = i1 * w.x;
      acc[0][kq * 4 + 1] = i0 * w.y;  acc[1][kq * 4 + 1] = i1 * w.y;
      acc[0][kq * 4 + 2] = i0 * w.z;  acc[1][kq * 4 + 2] = i1 * w.z;
      acc[0][kq * 4 + 3] = i0 * w.w;  acc[1][kq * 4 + 3] = i1 * w.w;
    }
  }
  for (int c = 0; c < 64; ++c) {
    const float r0 = rhS[(2 * np) * 66 + c];
    const float r1 = rhS[(2 * np + 1) * 66 + c];
#pragma unroll
    for (int kq = 0; kq < 4; ++kq) {
      const int kq2 = (kq + og2) & 3;
      const float4 w = *(const float4*)&W2s[(c + 1) * 64 + og2 * 16 + kq2 * 4];
      acc[0][kq * 4 + 0] += r0 * w.x;  acc[1][kq * 4 + 0] += r1 * w.x;
      acc[0][kq * 4 + 1] += r0 * w.y;  acc[1][kq * 4 + 1] += r1 * w.y;
      acc[0][kq * 4 + 2] += r0 * w.z;  acc[1][kq * 4 + 2] += r1 * w.z;
      acc[0][kq * 4 + 3] += r0 * w.w;  acc[1][kq * 4 + 3] += r1 * w.w;
    }
  }
  // Stage packed bf16 pairs: y2S[o2][np] = (node 2np, node 2np+1)
#pragma unroll
  for (int kq = 0; kq < 4; ++kq) {
    const int kq2 = (kq + og2) & 3;
#pragma unroll
    for (int j = 0; j < 4; ++j) {
      const int o2 = og2 * 16 + kq2 * 4 + j;
      y2S[o2 * 65 + np] = pack_bf16(acc[0][kq * 4 + j], acc[1][kq * 4 + j]);
    }
  }
  __syncthreads();
  // Coalesced writeback: 64 rows x 64 uints (128 nodes) each.
  for (int i = t; i < 64 * 64; i += 256) {
    const int o2 = i >> 6, npair = i & 63;
    *(unsigned*)&Y2t[(size_t)(b * 64 + o2) * NN + n0 + 2 * npair] = y2S[o2 * 65 + npair];
  }
}

__global__ __launch_bounds__(256) void k_final(const float* __restrict__ cpre,
                                               const float* __restrict__ ubuf,
                                               const float* __restrict__ hid,
                                               const float* __restrict__ b2,
                                               float* __restrict__ out) {
  size_t i4 = (size_t)blockIdx.x * 256 + threadIdx.x;  // 2,097,152 threads
  size_t base = i4 * 4;
  int b = (int)(base / (NN * NH));
  int rem = (int)(base % (NN * NH));
  int n = rem / NH, h0 = rem % NH;
  const float4 u = *(const float4*)&ubuf[base];
  const float4 hv = *(const float4*)&hid[base];
  const size_t ci = (size_t)n * NC2 + b * 64 + h0;
  const float4 cp0 = *(const float4*)&cpre[ci];
  const float4 cp1 = *(const float4*)&cpre[(size_t)NN * NC2 + ci];
  const float4 bb = *(const float4*)&b2[h0];
  float4 r;
  r.x = u.x * hv.x + (1.f - u.x) * tanhf(cp0.x + cp1.x + bb.x);
  r.y = u.y * hv.y + (1.f - u.y) * tanhf(cp0.y + cp1.y + bb.y);
  r.z = u.z * hv.z + (1.f - u.z) * tanhf(cp0.z + cp1.z + bb.z);
  r.w = u.w * hv.w + (1.f - u.w) * tanhf(cp0.w + cp1.w + bb.w);
  *(float4*)&out[base] = r;
}

extern "C" void kernel_launch(void* const* d_in, const int* in_sizes, int n_in,
                              void* d_out, int out_size, void* d_ws, size_t ws_size,
                              hipStream_t stream) {
  const float* inp = (const float*)d_in[0];
  const float* hid = (const float*)d_in[1];
  const float* adj = (const float*)d_in[2];
  const float* W1  = (const float*)d_in[3];
  const float* b1  = (const float*)d_in[4];
  const float* W2  = (const float*)d_in[5];
  const float* b2  = (const float*)d_in[6];
  float* out = (float*)d_out;

  char* w = (char*)d_ws;
  float* dd            = (float*)w;                       w += 8192;
  __hip_bfloat16* Abf  = (__hip_bfloat16*)w;              w += (size_t)NN * NN * 2;            // 8.39 MB
  __hip_bfloat16* X1t  = (__hip_bfloat16*)w;              w += (size_t)NC1P * NN * 2;          // 17.3 MB
  char* axreg          = w;                               w += (size_t)2 * NN * NC1P * 4;      // 69.2 MB union
  __hip_bfloat16* Y2t  = (__hip_bfloat16*)w;              w += (size_t)NC2 * NN * 2;           // 16.8 MB
  float* ubuf          = (float*)w;                       w += (size_t)NB * NN * NH * 4;       // 33.6 MB
  __hip_bfloat16* ax1bf = (__hip_bfloat16*)axreg;  // 2 x 17.3 MB bf16 split-K partials
  float* cpre           = (float*)axreg;           // 2 x 33.5 MB f32 (ax1bf dead by then)
  __hip_bfloat16* rhG  = X1t;                      // X1t dead after GEMM1

  k_deg<<<NN, 256, 0, stream>>>(adj, dd);
  k_buildA<<<dim3(32, 32), 256, 0, stream>>>(adj, dd, Abf);
  k_buildX1<<<dim3(NB, 32), 256, 0, stream>>>(inp, hid, X1t);
  k_zeropad<<<512, 256, 0, stream>>>(X1t);
  k_gemm_bt<true><<<dim3(16, 33, 2), 256, 0, stream>>>(Abf, X1t, ax1bf, NC1P, NN / 2);
  k_out1<<<dim3(NB, 16), 256, 0, stream>>>(ax1bf, W1, b1, hid, rhG, ubuf);
  k_y2<<<dim3(NB, 16), 256, 0, stream>>>(rhG, inp, W2, Y2t);
  k_gemm_bt<false><<<dim3(16, 32, 2), 256, 0, stream>>>(Abf, Y2t, cpre, NC2, NN / 2);
  k_final<<<8192, 256, 0, stream>>>(cpre, ubuf, hid, b2, out);
}